// Round 1
// baseline (420.400 us; speedup 1.0000x reference)
//
#include <hip/hip_runtime.h>

#define LDA 136   // padded LDS row stride (bf16 elems): 136%32-words => ~2-way (free) bank aliasing
#define TM  64    // atoms per block

// W3J112 constant (3,3,5), already divided by sqrt(5). idx = i*15 + j*5 + k
__constant__ float W3J[45] = {
  0.f, 0.f, -0.18257418583505536f, 0.f, -0.31622776601683794f,
  0.f, 0.31622776601683794f, 0.f, 0.f, 0.f,
  0.31622776601683794f, 0.f, 0.f, 0.f, 0.f,
  0.f, 0.31622776601683794f, 0.f, 0.f, 0.f,
  0.f, 0.f, 0.36514837167011072f, 0.f, 0.f,
  0.f, 0.f, 0.f, 0.31622776601683794f, 0.f,
  0.31622776601683794f, 0.f, 0.f, 0.f, 0.f,
  0.f, 0.f, 0.f, 0.31622776601683794f, 0.f,
  0.f, 0.f, -0.18257418583505536f, 0.f, 0.31622776601683794f
};

__device__ __forceinline__ unsigned short f2bf(float f) {
  unsigned int u = __float_as_uint(f);
  u += 0x7FFFu + ((u >> 16) & 1u);   // round-to-nearest-even
  return (unsigned short)(u >> 16);
}

// Build Bt[n][k] = M[k][n] in bf16, padded to 128x128 with zeros.
// out[z,n] = sum_k geom[z,k] * M[k][n]
__global__ void build_B_kernel(
    const float* __restrict__ field,
    const float* __restrict__ w000, const float* __restrict__ w011,
    const float* __restrict__ w101, const float* __restrict__ w110,
    const float* __restrict__ w112, const float* __restrict__ w202,
    const float* __restrict__ w211, const float* __restrict__ wl0,
    const float* __restrict__ wl1,  const float* __restrict__ wl2,
    unsigned short* __restrict__ Bt)
{
  const float C0  = 0.02795084971874737f;   // sqrt(1/1280)
  const float C1  = 0.051031036307982884f;  // sqrt(3/1152)
  const float C2  = 0.09882117688026186f;   // sqrt(5/512)
  const float IS3 = 0.57735026918962576f;
  const float IS5 = 0.44721359549995794f;

  int n = blockIdx.x;    // output col 0..127
  int k = threadIdx.x;   // input row  0..127
  float val = 0.0f;

  if (n < 120 && k < 120) {
    if (n < 32) {
      int w = n;
      if (k < 32) {                 // g0 -> out0
        int u = k;
        float a = 0.f;
        for (int v = 0; v < 32; ++v) a += w000[u*1024 + v*32 + w] * field[v];
        val = C0 * a + wl0[u*32 + w] * 0.17677669529663689f;
      } else if (k < 80) {          // g1 -> out0 (110)
        int u = (k-32)/3, i = (k-32)%3;
        float a = 0.f;
        for (int v = 0; v < 16; ++v) a += w110[u*512 + v*32 + w] * field[32 + v*3 + i];
        val = C0 * IS3 * a;
      }                             // g2 -> out0 : zero
    } else if (n < 80) {
      int w = (n-32)/3, j = (n-32)%3;
      if (k < 32) {                 // g0 -> out1 (011)
        int u = k;
        float a = 0.f;
        for (int v = 0; v < 16; ++v) a += w011[u*256 + v*16 + w] * field[32 + v*3 + j];
        val = C1 * IS3 * a;
      } else if (k < 80) {          // g1 -> out1 (101 + residual), spatial-diagonal
        int u = (k-32)/3, i = (k-32)%3;
        if (i == j) {
          float a = 0.f;
          for (int v = 0; v < 32; ++v) a += w101[u*512 + v*16 + w] * field[v];
          val = C1 * IS3 * a + wl1[u*16 + w] * 0.25f;
        }
      } else {                      // g2 -> out1 (211 x W3J)
        int u = (k-80)/5, kk = (k-80)%5;
        float c0w = W3J[0*15 + j*5 + kk];
        float c1w = W3J[1*15 + j*5 + kk];
        float c2w = W3J[2*15 + j*5 + kk];
        float a = 0.f;
        for (int v = 0; v < 16; ++v) {
          float s = c0w*field[32+v*3+0] + c1w*field[32+v*3+1] + c2w*field[32+v*3+2];
          a += w211[u*256 + v*16 + w] * s;
        }
        val = C1 * a;
      }
    } else {
      int w = (n-80)/5, k2 = (n-80)%5;
      if (k >= 32 && k < 80) {      // g1 -> out2 (112 x W3J)
        int u = (k-32)/3, i = (k-32)%3;
        float c0w = W3J[i*15 + 0*5 + k2];
        float c1w = W3J[i*15 + 1*5 + k2];
        float c2w = W3J[i*15 + 2*5 + k2];
        float a = 0.f;
        for (int v = 0; v < 16; ++v) {
          float s = c0w*field[32+v*3+0] + c1w*field[32+v*3+1] + c2w*field[32+v*3+2];
          a += w112[u*128 + v*8 + w] * s;
        }
        val = C2 * a;
      } else if (k >= 80) {         // g2 -> out2 (202 + residual), spatial-diagonal
        int u = (k-80)/5, kk = (k-80)%5;
        if (kk == k2) {
          float a = 0.f;
          for (int v = 0; v < 32; ++v) a += w202[u*256 + v*8 + w] * field[v];
          val = C2 * IS5 * a + wl2[u*8 + w] * 0.35355339059327378f;
        }
      }                             // g0 -> out2 : zero
    }
  }
  Bt[n*128 + k] = f2bf(val);
}

typedef __attribute__((ext_vector_type(8))) __bf16 bf16x8;
typedef __attribute__((ext_vector_type(4))) float  f32x4;

// out(500000x120) = geom(500000x120) @ M(120x120), bf16 MFMA 16x16x32, fp32 accum.
__global__ __launch_bounds__(256) void coupling_main(
    const float* __restrict__ geom, const unsigned short* __restrict__ Btg,
    float* __restrict__ out, int natoms)
{
  __shared__ alignas(16) unsigned short Alds[TM  * LDA];  // 17408 B
  __shared__ alignas(16) unsigned short Blds[128 * LDA];  // 34816 B

  int tid = threadIdx.x;
  long long base = (long long)blockIdx.x * TM;

  // stage B (128x128 bf16) into LDS with padded stride; hot in L2 across blocks
  #pragma unroll
  for (int r = 0; r < 8; ++r) {
    int g   = tid + r * 256;        // 0..2047 groups of 8 bf16
    int row = g >> 4;
    int col = (g & 15) * 8;
    uint4 v = ((const uint4*)Btg)[g];
    *((uint4*)&Blds[row * LDA + col]) = v;
  }
  // zero A pad cols 120..127 (so k-loop over 128 adds exact zeros)
  if (tid < TM) {
    *((uint4*)&Alds[tid * LDA + 120]) = make_uint4(0u, 0u, 0u, 0u);
  }
  // stage A tile: 64 atoms x 120 f32 -> bf16 (globally contiguous, fully coalesced)
  #pragma unroll
  for (int r = 0; r < 4; ++r) {
    int g = tid + r * 256;          // 0..959 groups of 8 floats
    if (g < 960) {
      int row = g / 15;
      int col = (g - row * 15) * 8;
      long long atom = base + row;
      uint4 pk;
      if (atom < natoms) {
        const float* src = geom + (long long)atom * 120 + col;
        float4 fa = ((const float4*)src)[0];
        float4 fb = ((const float4*)src)[1];
        pk.x = ((unsigned)f2bf(fa.y) << 16) | f2bf(fa.x);
        pk.y = ((unsigned)f2bf(fa.w) << 16) | f2bf(fa.z);
        pk.z = ((unsigned)f2bf(fb.y) << 16) | f2bf(fb.x);
        pk.w = ((unsigned)f2bf(fb.w) << 16) | f2bf(fb.z);
      } else {
        pk = make_uint4(0u, 0u, 0u, 0u);
      }
      *((uint4*)&Alds[row * LDA + col]) = pk;
    }
  }
  __syncthreads();

  int lane = tid & 63;
  int wave = tid >> 6;
  int mrow = lane & 15;   // A row / C col within 16-tile
  int kq   = lane >> 4;   // k-quad

  f32x4 zero = {0.f, 0.f, 0.f, 0.f};
  f32x4 acc[8];
  #pragma unroll
  for (int t = 0; t < 8; ++t) acc[t] = zero;

  const unsigned short* arow = &Alds[(wave * 16 + mrow) * LDA + kq * 8];
  const unsigned short* brow = &Blds[mrow * LDA + kq * 8];

  #pragma unroll
  for (int ks = 0; ks < 4; ++ks) {
    bf16x8 af = __builtin_bit_cast(bf16x8, *(const uint4*)(arow + ks * 32));
    #pragma unroll
    for (int t = 0; t < 8; ++t) {
      bf16x8 bf_ = __builtin_bit_cast(bf16x8, *(const uint4*)(brow + t * 16 * LDA + ks * 32));
      acc[t] = __builtin_amdgcn_mfma_f32_16x16x32_bf16(af, bf_, acc[t], 0, 0, 0);
    }
  }

  // C/D layout: col = lane&15, row = (lane>>4)*4 + reg   [measured m89/m91]
  long long atom0 = base + wave * 16 + kq * 4;
  #pragma unroll
  for (int t = 0; t < 8; ++t) {
    int n = t * 16 + mrow;
    if (n < 120) {
      #pragma unroll
      for (int r2 = 0; r2 < 4; ++r2) {
        long long atom = atom0 + r2;
        if (atom < natoms) out[atom * 120 + n] = acc[t][r2];
      }
    }
  }
}

extern "C" void kernel_launch(void* const* d_in, const int* in_sizes, int n_in,
                              void* d_out, int out_size, void* d_ws, size_t ws_size,
                              hipStream_t stream) {
  const float* geom  = (const float*)d_in[0];
  const float* field = (const float*)d_in[1];
  const float* w000  = (const float*)d_in[2];
  const float* w011  = (const float*)d_in[3];
  const float* w101  = (const float*)d_in[4];
  const float* w110  = (const float*)d_in[5];
  const float* w112  = (const float*)d_in[6];
  const float* w202  = (const float*)d_in[7];
  const float* w211  = (const float*)d_in[8];
  const float* wl0   = (const float*)d_in[9];
  const float* wl1   = (const float*)d_in[10];
  const float* wl2   = (const float*)d_in[11];
  float* out = (float*)d_out;
  unsigned short* Bt = (unsigned short*)d_ws;   // 128*128 bf16 = 32 KB

  int natoms = in_sizes[0] / 120;

  build_B_kernel<<<dim3(128), dim3(128), 0, stream>>>(
      field, w000, w011, w101, w110, w112, w202, w211, wl0, wl1, wl2, Bt);

  int ntiles = (natoms + TM - 1) / TM;
  coupling_main<<<dim3(ntiles), dim3(256), 0, stream>>>(geom, Bt, out, natoms);
}